// Round 1
// baseline (321.452 us; speedup 1.0000x reference)
//
#include <hip/hip_runtime.h>

// NCC loss, (B=2, C=1, 160^3) f32, 9^3 box window, separable 3-pass + fused reduce.

constexpr int W = 160, H = 160, D = 160;
constexpr int SLICE = W * H;          // 25600
constexpr int NVOX  = W * H * D;      // 4,096,000 per batch item
constexpr int BATCH = 2;
constexpr int TPB   = 256;
constexpr int NBLK  = (NVOX + TPB - 1) / TPB;  // 16000
constexpr int RAD   = 4;
constexpr float WIN_SIZE = 729.0f;

// ---------------- pass 1: window-sum along W, fusing the 5 products -------
__global__ __launch_bounds__(TPB) void pass_w(const float* __restrict__ I,
                                              const float* __restrict__ J,
                                              float* __restrict__ out) {
    int idx = blockIdx.x * TPB + threadIdx.x;
    if (idx >= NVOX) return;
    int x = idx % W;
    int rowbase = idx - x;
    int lo = x - RAD < 0 ? 0 : x - RAD;
    int hi = x + RAD > W - 1 ? W - 1 : x + RAD;
    float s0 = 0.f, s1 = 0.f, s2 = 0.f, s3 = 0.f, s4 = 0.f;
    for (int xx = lo; xx <= hi; ++xx) {
        float a = I[rowbase + xx];
        float b = J[rowbase + xx];
        s0 += a; s1 += b; s2 += a * a; s3 += b * b; s4 += a * b;
    }
    out[idx]            = s0;
    out[idx +     NVOX] = s1;
    out[idx + 2 * NVOX] = s2;
    out[idx + 3 * NVOX] = s3;
    out[idx + 4 * NVOX] = s4;
}

// ---------------- pass 2: window-sum along H (stride W) -------------------
__global__ __launch_bounds__(TPB) void pass_h(const float* __restrict__ in,
                                              float* __restrict__ out) {
    int idx = blockIdx.x * TPB + threadIdx.x;
    if (idx >= NVOX) return;
    int y = (idx / W) % H;
    int base = idx - y * W;
    int lo = y - RAD < 0 ? 0 : y - RAD;
    int hi = y + RAD > H - 1 ? H - 1 : y + RAD;
    float s[5] = {0.f, 0.f, 0.f, 0.f, 0.f};
    for (int yy = lo; yy <= hi; ++yy) {
        int a = base + yy * W;
#pragma unroll
        for (int f = 0; f < 5; ++f) s[f] += in[a + f * NVOX];
    }
#pragma unroll
    for (int f = 0; f < 5; ++f) out[idx + f * NVOX] = s[f];
}

// ---------------- pass 3: window-sum along D (stride SLICE) + cc + reduce -
__global__ __launch_bounds__(TPB) void pass_d_cc(const float* __restrict__ in,
                                                 double* __restrict__ partials) {
    int idx = blockIdx.x * TPB + threadIdx.x;
    float cc = 0.f;
    if (idx < NVOX) {
        int z = idx / SLICE;
        int base = idx - z * SLICE;
        int lo = z - RAD < 0 ? 0 : z - RAD;
        int hi = z + RAD > D - 1 ? D - 1 : z + RAD;
        float s[5] = {0.f, 0.f, 0.f, 0.f, 0.f};
        for (int zz = lo; zz <= hi; ++zz) {
            int a = base + zz * SLICE;
#pragma unroll
            for (int f = 0; f < 5; ++f) s[f] += in[a + f * NVOX];
        }
        float Is = s[0], Js = s[1], I2s = s[2], J2s = s[3], IJs = s[4];
        float uI = Is * (1.0f / WIN_SIZE);
        float uJ = Js * (1.0f / WIN_SIZE);
        float cross = IJs - uJ * Is - uI * Js + uI * uJ * WIN_SIZE;
        float Ivar  = I2s - 2.0f * uI * Is + uI * uI * WIN_SIZE;
        float Jvar  = J2s - 2.0f * uJ * Js + uJ * uJ * WIN_SIZE;
        cc = cross * cross / (Ivar * Jvar + 1e-5f);
    }
    // deterministic block reduction in double
    double v = (double)cc;
#pragma unroll
    for (int off = 32; off > 0; off >>= 1) v += __shfl_down(v, off);
    __shared__ double sm[TPB / 64];
    int lane = threadIdx.x & 63, wid = threadIdx.x >> 6;
    if (lane == 0) sm[wid] = v;
    __syncthreads();
    if (threadIdx.x == 0) {
        double t = 0.0;
#pragma unroll
        for (int i = 0; i < TPB / 64; ++i) t += sm[i];
        partials[blockIdx.x] = t;
    }
}

// ---------------- final deterministic reduce ------------------------------
__global__ __launch_bounds__(TPB) void finalize(const double* __restrict__ p,
                                                int n, float* __restrict__ out) {
    double v = 0.0;
    for (int i = threadIdx.x; i < n; i += TPB) v += p[i];
#pragma unroll
    for (int off = 32; off > 0; off >>= 1) v += __shfl_down(v, off);
    __shared__ double sm[TPB / 64];
    int lane = threadIdx.x & 63, wid = threadIdx.x >> 6;
    if (lane == 0) sm[wid] = v;
    __syncthreads();
    if (threadIdx.x == 0) {
        double t = 0.0;
#pragma unroll
        for (int i = 0; i < TPB / 64; ++i) t += sm[i];
        out[0] = (float)(1.0 - t / (double)((double)BATCH * (double)NVOX));
    }
}

extern "C" void kernel_launch(void* const* d_in, const int* in_sizes, int n_in,
                              void* d_out, int out_size, void* d_ws, size_t ws_size,
                              hipStream_t stream) {
    const float* I = (const float*)d_in[0];
    const float* J = (const float*)d_in[1];
    float* out = (float*)d_out;

    // ws layout: bufA (5*NVOX f32) | bufB (5*NVOX f32) | partials (2*NBLK f64)
    float*  bufA = (float*)d_ws;
    float*  bufB = bufA + (size_t)5 * NVOX;
    double* partials = (double*)(bufB + (size_t)5 * NVOX);

    for (int b = 0; b < BATCH; ++b) {
        const float* Ib = I + (size_t)b * NVOX;
        const float* Jb = J + (size_t)b * NVOX;
        pass_w<<<NBLK, TPB, 0, stream>>>(Ib, Jb, bufA);
        pass_h<<<NBLK, TPB, 0, stream>>>(bufA, bufB);
        pass_d_cc<<<NBLK, TPB, 0, stream>>>(bufB, partials + (size_t)b * NBLK);
    }
    finalize<<<1, TPB, 0, stream>>>(partials, BATCH * NBLK, out);
}

// Round 2
// 127.937 us; speedup vs baseline: 2.5126x; 2.5126x over previous
//
#include <hip/hip_runtime.h>

// NCC loss (B=2, C=1, 160^3 f32, 9^3 box window).
// Separable passes reordered z -> y -> x, with per-thread sliding-window
// running sums for z and y (2 reads/step instead of 9 taps), bf16
// intermediates (halves traffic), and the x-pass fused with the cc
// expression + deterministic reduction.

constexpr int W = 160, H = 160, D = 160;
constexpr int SLICE = W * H;           // 25600
constexpr int NVOX  = W * H * D;       // 4,096,000
constexpr int BATCH = 2;
constexpr int TPB   = 256;
constexpr int XG    = W / 8;           // 20 thread-groups of 8 x each
constexpr int CHZ   = 10, NCHZ = D / CHZ;   // z chunks
constexpr int CHY   = 10, NCHY = H / CHY;   // y chunks
constexpr float WIN_SIZE = 729.0f;

constexpr int NTH_P1 = BATCH * XG * H * NCHZ;   // 102400
constexpr int NTH_P2 = BATCH * XG * D * NCHY;   // 102400
constexpr int NTH_P3 = BATCH * XG * H * D;      // 1,024,000
constexpr int NBLK_P3 = NTH_P3 / TPB;           // 4000

// ---- bf16 helpers (RTNE) -------------------------------------------------
__device__ inline unsigned short f2bf(float f) {
    unsigned int u = __builtin_bit_cast(unsigned int, f);
    u += 0x7fffu + ((u >> 16) & 1u);
    return (unsigned short)(u >> 16);
}
__device__ inline float bf2f(unsigned short h) {
    unsigned int u = ((unsigned int)h) << 16;
    return __builtin_bit_cast(float, u);
}
__device__ inline unsigned int pack2(float lo, float hi) {
    return (unsigned int)f2bf(lo) | ((unsigned int)f2bf(hi) << 16);
}
__device__ inline void unpack8(uint4 v, float* o) {
    o[0] = bf2f((unsigned short)(v.x & 0xffffu)); o[1] = bf2f((unsigned short)(v.x >> 16));
    o[2] = bf2f((unsigned short)(v.y & 0xffffu)); o[3] = bf2f((unsigned short)(v.y >> 16));
    o[4] = bf2f((unsigned short)(v.z & 0xffffu)); o[5] = bf2f((unsigned short)(v.z >> 16));
    o[6] = bf2f((unsigned short)(v.w & 0xffffu)); o[7] = bf2f((unsigned short)(v.w >> 16));
}

// ---- pass 1: products + sliding window-sum along z -----------------------
__global__ __launch_bounds__(TPB) void pass_z(const float* __restrict__ I,
                                              const float* __restrict__ J,
                                              unsigned short* __restrict__ outA) {
    int t = blockIdx.x * TPB + threadIdx.x;
    if (t >= NTH_P1) return;
    int xg = t % XG;
    int y  = (t / XG) % H;
    int c  = (t / (XG * H)) % NCHZ;
    int b  = t / (XG * H * NCHZ);
    int x0 = xg * 8;
    const float* Ib = I + (size_t)b * NVOX + y * W + x0;
    const float* Jb = J + (size_t)b * NVOX + y * W + x0;
    size_t obase = (size_t)(b * 5) * NVOX + (size_t)y * W + x0;

    float s[5][8];
#pragma unroll
    for (int f = 0; f < 5; ++f)
#pragma unroll
        for (int i = 0; i < 8; ++i) s[f][i] = 0.f;

    auto addSlice = [&](int zz) {
        const float4* ip = (const float4*)(Ib + (size_t)zz * SLICE);
        const float4* jp = (const float4*)(Jb + (size_t)zz * SLICE);
        float4 a0 = ip[0], a1 = ip[1], b0 = jp[0], b1 = jp[1];
        float av[8] = {a0.x, a0.y, a0.z, a0.w, a1.x, a1.y, a1.z, a1.w};
        float bv[8] = {b0.x, b0.y, b0.z, b0.w, b1.x, b1.y, b1.z, b1.w};
#pragma unroll
        for (int i = 0; i < 8; ++i) {
            float a = av[i], bb = bv[i];
            s[0][i] += a; s[1][i] += bb;
            s[2][i] += a * a; s[3][i] += bb * bb; s[4][i] += a * bb;
        }
    };
    auto subSlice = [&](int zz) {
        const float4* ip = (const float4*)(Ib + (size_t)zz * SLICE);
        const float4* jp = (const float4*)(Jb + (size_t)zz * SLICE);
        float4 a0 = ip[0], a1 = ip[1], b0 = jp[0], b1 = jp[1];
        float av[8] = {a0.x, a0.y, a0.z, a0.w, a1.x, a1.y, a1.z, a1.w};
        float bv[8] = {b0.x, b0.y, b0.z, b0.w, b1.x, b1.y, b1.z, b1.w};
#pragma unroll
        for (int i = 0; i < 8; ++i) {
            float a = av[i], bb = bv[i];
            s[0][i] -= a; s[1][i] -= bb;
            s[2][i] -= a * a; s[3][i] -= bb * bb; s[4][i] -= a * bb;
        }
    };

    int z0 = c * CHZ;
    for (int zz = z0 - 4; zz <= z0 + 4; ++zz)
        if (zz >= 0 && zz < D) addSlice(zz);

    for (int dz = 0; dz < CHZ; ++dz) {
        int z = z0 + dz;
#pragma unroll
        for (int f = 0; f < 5; ++f) {
            uint4 o;
            o.x = pack2(s[f][0], s[f][1]);
            o.y = pack2(s[f][2], s[f][3]);
            o.z = pack2(s[f][4], s[f][5]);
            o.w = pack2(s[f][6], s[f][7]);
            *(uint4*)(outA + obase + (size_t)f * NVOX + (size_t)z * SLICE) = o;
        }
        int za = z + 5; if (za < D) addSlice(za);
        int zs = z - 4; if (zs >= 0) subSlice(zs);
    }
}

// ---- pass 2: sliding window-sum along y ----------------------------------
__global__ __launch_bounds__(TPB) void pass_y(const unsigned short* __restrict__ inA,
                                              unsigned short* __restrict__ outB) {
    int t = blockIdx.x * TPB + threadIdx.x;
    if (t >= NTH_P2) return;
    int xg = t % XG;
    int z  = (t / XG) % D;
    int c  = (t / (XG * D)) % NCHY;
    int b  = t / (XG * D * NCHY);
    int x0 = xg * 8;
    size_t base = (size_t)(b * 5) * NVOX + (size_t)z * SLICE + x0;

    float s[5][8];
#pragma unroll
    for (int f = 0; f < 5; ++f)
#pragma unroll
        for (int i = 0; i < 8; ++i) s[f][i] = 0.f;

    auto addRow = [&](int yy) {
#pragma unroll
        for (int f = 0; f < 5; ++f) {
            uint4 v = *(const uint4*)(inA + base + (size_t)f * NVOX + (size_t)yy * W);
            float u[8]; unpack8(v, u);
#pragma unroll
            for (int i = 0; i < 8; ++i) s[f][i] += u[i];
        }
    };
    auto subRow = [&](int yy) {
#pragma unroll
        for (int f = 0; f < 5; ++f) {
            uint4 v = *(const uint4*)(inA + base + (size_t)f * NVOX + (size_t)yy * W);
            float u[8]; unpack8(v, u);
#pragma unroll
            for (int i = 0; i < 8; ++i) s[f][i] -= u[i];
        }
    };

    int y0 = c * CHY;
    for (int yy = y0 - 4; yy <= y0 + 4; ++yy)
        if (yy >= 0 && yy < H) addRow(yy);

    for (int dy = 0; dy < CHY; ++dy) {
        int y = y0 + dy;
#pragma unroll
        for (int f = 0; f < 5; ++f) {
            uint4 o;
            o.x = pack2(s[f][0], s[f][1]);
            o.y = pack2(s[f][2], s[f][3]);
            o.z = pack2(s[f][4], s[f][5]);
            o.w = pack2(s[f][6], s[f][7]);
            *(uint4*)(outB + base + (size_t)f * NVOX + (size_t)y * W) = o;
        }
        int ya = y + 5; if (ya < H) addRow(ya);
        int ys = y - 4; if (ys >= 0) subRow(ys);
    }
}

// ---- pass 3: window-sum along x (registers) + cc + block reduce ----------
__global__ __launch_bounds__(TPB) void pass_x_cc(const unsigned short* __restrict__ inB,
                                                 double* __restrict__ partials) {
    int t = blockIdx.x * TPB + threadIdx.x;
    int xg = t % XG;
    int y  = (t / XG) % H;
    int z  = (t / (XG * H)) % D;
    int b  = t / (XG * H * D);
    int x0 = xg * 8;
    size_t base = (size_t)(b * 5) * NVOX + (size_t)z * SLICE + (size_t)y * W;

    float wsum[5][8];
#pragma unroll
    for (int f = 0; f < 5; ++f) {
        float v[24];
        if (xg > 0) {
            uint4 l = *(const uint4*)(inB + base + (size_t)f * NVOX + x0 - 8);
            unpack8(l, v);
        } else {
#pragma unroll
            for (int k = 0; k < 8; ++k) v[k] = 0.f;
        }
        {
            uint4 m = *(const uint4*)(inB + base + (size_t)f * NVOX + x0);
            unpack8(m, v + 8);
        }
        if (xg < XG - 1) {
            uint4 r = *(const uint4*)(inB + base + (size_t)f * NVOX + x0 + 8);
            unpack8(r, v + 16);
        } else {
#pragma unroll
            for (int k = 16; k < 24; ++k) v[k] = 0.f;
        }
        float s = 0.f;
#pragma unroll
        for (int j = 4; j <= 12; ++j) s += v[j];
        wsum[f][0] = s;
#pragma unroll
        for (int i = 1; i < 8; ++i) { s += v[12 + i] - v[3 + i]; wsum[f][i] = s; }
    }

    double acc = 0.0;
#pragma unroll
    for (int i = 0; i < 8; ++i) {
        float Is = wsum[0][i], Js = wsum[1][i];
        float I2s = wsum[2][i], J2s = wsum[3][i], IJs = wsum[4][i];
        float uI = Is * (1.0f / WIN_SIZE);
        float uJ = Js * (1.0f / WIN_SIZE);
        float cross = IJs - uJ * Is - uI * Js + uI * uJ * WIN_SIZE;
        float Ivar  = I2s - 2.0f * uI * Is + uI * uI * WIN_SIZE;
        float Jvar  = J2s - 2.0f * uJ * Js + uJ * uJ * WIN_SIZE;
        acc += (double)(cross * cross / (Ivar * Jvar + 1e-5f));
    }

#pragma unroll
    for (int off = 32; off > 0; off >>= 1) acc += __shfl_down(acc, off);
    __shared__ double sm[TPB / 64];
    int lane = threadIdx.x & 63, wid = threadIdx.x >> 6;
    if (lane == 0) sm[wid] = acc;
    __syncthreads();
    if (threadIdx.x == 0) {
        double tt = 0.0;
#pragma unroll
        for (int i = 0; i < TPB / 64; ++i) tt += sm[i];
        partials[blockIdx.x] = tt;
    }
}

// ---- final deterministic reduce ------------------------------------------
__global__ __launch_bounds__(TPB) void finalize(const double* __restrict__ p,
                                                float* __restrict__ out) {
    double v = 0.0;
    for (int i = threadIdx.x; i < NBLK_P3; i += TPB) v += p[i];
#pragma unroll
    for (int off = 32; off > 0; off >>= 1) v += __shfl_down(v, off);
    __shared__ double sm[TPB / 64];
    int lane = threadIdx.x & 63, wid = threadIdx.x >> 6;
    if (lane == 0) sm[wid] = v;
    __syncthreads();
    if (threadIdx.x == 0) {
        double t = 0.0;
#pragma unroll
        for (int i = 0; i < TPB / 64; ++i) t += sm[i];
        out[0] = (float)(1.0 - t / (double)((double)BATCH * (double)NVOX));
    }
}

extern "C" void kernel_launch(void* const* d_in, const int* in_sizes, int n_in,
                              void* d_out, int out_size, void* d_ws, size_t ws_size,
                              hipStream_t stream) {
    const float* I = (const float*)d_in[0];
    const float* J = (const float*)d_in[1];
    float* out = (float*)d_out;

    // ws layout: bufA (2*5*NVOX bf16) | bufB (2*5*NVOX bf16) | partials (4000 f64)
    unsigned short* bufA = (unsigned short*)d_ws;
    unsigned short* bufB = bufA + (size_t)BATCH * 5 * NVOX;
    double* partials = (double*)(bufB + (size_t)BATCH * 5 * NVOX);

    pass_z<<<NTH_P1 / TPB, TPB, 0, stream>>>(I, J, bufA);
    pass_y<<<NTH_P2 / TPB, TPB, 0, stream>>>(bufA, bufB);
    pass_x_cc<<<NBLK_P3, TPB, 0, stream>>>(bufB, partials);
    finalize<<<1, TPB, 0, stream>>>(partials, out);
}

// Round 3
// 118.442 us; speedup vs baseline: 2.7140x; 1.0802x over previous
//
#include <hip/hip_runtime.h>

// NCC loss (B=2, C=1, 160^3 f32, 9^3 box window).
// pass_z: products + sliding z-window (4-x threads, chunked, high occupancy)
// pass_yx: fused sliding y-window (registers) + x-window via LDS row staging
//          + cc expression + deterministic block reduction. No bufB.
// finalize: deterministic reduce of block partials.

constexpr int W = 160, H = 160, D = 160;
constexpr int SLICE = W * H;           // 25600
constexpr int NVOX  = W * H * D;       // 4,096,000
constexpr int BATCH = 2;
constexpr float WIN_SIZE = 729.0f;

// pass_z geometry
constexpr int TPB_Z = 256;
constexpr int XG4   = W / 4;                 // 40 groups of 4 x
constexpr int CHZ   = 8, NCHZ = D / CHZ;     // 20 z-chunks
constexpr int NTH_Z = BATCH * XG4 * H * NCHZ;    // 256,000
constexpr int NBLK_Z = NTH_Z / TPB_Z;            // 1000

// pass_yx geometry
constexpr int TPB_YX = 320;                  // 16 row-tuples x 20 xg
constexpr int GRP    = 16;
constexpr int XG     = W / 8;                // 20 groups of 8 x
constexpr int CHY    = 5, NCHY = H / CHY;    // 32 y-chunks
constexpr int NTUP   = BATCH * D * NCHY;     // 10240 (b,z,yc) tuples
constexpr int NBLK_YX = NTUP / GRP;          // 640
constexpr int LROW   = 176;                  // 8 pad | 160 | 8 pad

// ---- bf16 helpers (RTNE) -------------------------------------------------
__device__ inline unsigned short f2bf(float f) {
    unsigned int u = __builtin_bit_cast(unsigned int, f);
    u += 0x7fffu + ((u >> 16) & 1u);
    return (unsigned short)(u >> 16);
}
__device__ inline float bf2f(unsigned short h) {
    unsigned int u = ((unsigned int)h) << 16;
    return __builtin_bit_cast(float, u);
}
__device__ inline unsigned int pack2(float lo, float hi) {
    return (unsigned int)f2bf(lo) | ((unsigned int)f2bf(hi) << 16);
}
__device__ inline void unpack8(uint4 v, float* o) {
    o[0] = bf2f((unsigned short)(v.x & 0xffffu)); o[1] = bf2f((unsigned short)(v.x >> 16));
    o[2] = bf2f((unsigned short)(v.y & 0xffffu)); o[3] = bf2f((unsigned short)(v.y >> 16));
    o[4] = bf2f((unsigned short)(v.z & 0xffffu)); o[5] = bf2f((unsigned short)(v.z >> 16));
    o[6] = bf2f((unsigned short)(v.w & 0xffffu)); o[7] = bf2f((unsigned short)(v.w >> 16));
}

// ---- pass 1: products + sliding window-sum along z -----------------------
__global__ __launch_bounds__(TPB_Z) void pass_z(const float* __restrict__ I,
                                                const float* __restrict__ J,
                                                unsigned short* __restrict__ outA) {
    int t = blockIdx.x * TPB_Z + threadIdx.x;
    int xg = t % XG4;
    int y  = (t / XG4) % H;
    int c  = (t / (XG4 * H)) % NCHZ;
    int b  = t / (XG4 * H * NCHZ);
    int x0 = xg * 4;
    const float* Ib = I + (size_t)b * NVOX + y * W + x0;
    const float* Jb = J + (size_t)b * NVOX + y * W + x0;
    size_t obase = (size_t)(b * 5) * NVOX + (size_t)y * W + x0;

    float s[5][4];
#pragma unroll
    for (int f = 0; f < 5; ++f)
#pragma unroll
        for (int i = 0; i < 4; ++i) s[f][i] = 0.f;

    auto tap = [&](int zz, float sgn) {
        float4 a = *(const float4*)(Ib + (size_t)zz * SLICE);
        float4 bb = *(const float4*)(Jb + (size_t)zz * SLICE);
        float av[4] = {a.x, a.y, a.z, a.w};
        float bv[4] = {bb.x, bb.y, bb.z, bb.w};
#pragma unroll
        for (int i = 0; i < 4; ++i) {
            float x = av[i], yv = bv[i];
            s[0][i] += sgn * x; s[1][i] += sgn * yv;
            s[2][i] += sgn * x * x; s[3][i] += sgn * yv * yv; s[4][i] += sgn * x * yv;
        }
    };

    int z0 = c * CHZ;
    for (int zz = z0 - 4; zz <= z0 + 4; ++zz)
        if (zz >= 0 && zz < D) tap(zz, 1.f);

    for (int dz = 0; dz < CHZ; ++dz) {
        int z = z0 + dz;
#pragma unroll
        for (int f = 0; f < 5; ++f) {
            uint2 o;
            o.x = pack2(s[f][0], s[f][1]);
            o.y = pack2(s[f][2], s[f][3]);
            *(uint2*)(outA + obase + (size_t)f * NVOX + (size_t)z * SLICE) = o;
        }
        int za = z + 5; if (za < D) tap(za, 1.f);
        int zs = z - 4; if (zs >= 0) tap(zs, -1.f);
    }
}

// ---- pass 2: fused y-window (regs) + x-window (LDS) + cc + reduce --------
__global__ __launch_bounds__(TPB_YX) void pass_yx(const unsigned short* __restrict__ inA,
                                                  double* __restrict__ partials) {
    __shared__ unsigned short lds[GRP][5][LROW];

    int tid = threadIdx.x;
    int g  = tid / XG;      // 0..15
    int xg = tid % XG;      // 0..19
    int tuple = blockIdx.x * GRP + g;
    int yc = tuple % NCHY;
    int z  = (tuple / NCHY) % D;
    int b  = tuple / (NCHY * D);
    int x0 = xg * 8;
    size_t base = (size_t)(b * 5) * NVOX + (size_t)z * SLICE + x0;

    // zero the halo pads once
    if (xg < 8) {
#pragma unroll
        for (int f = 0; f < 5; ++f) {
            lds[g][f][xg] = 0;
            lds[g][f][W + 8 + xg] = 0;
        }
    }

    float s[5][8];
#pragma unroll
    for (int f = 0; f < 5; ++f)
#pragma unroll
        for (int i = 0; i < 8; ++i) s[f][i] = 0.f;

    auto tapRow = [&](int yy, bool add) {
#pragma unroll
        for (int f = 0; f < 5; ++f) {
            uint4 v = *(const uint4*)(inA + base + (size_t)f * NVOX + (size_t)yy * W);
            float u[8]; unpack8(v, u);
            if (add) {
#pragma unroll
                for (int i = 0; i < 8; ++i) s[f][i] += u[i];
            } else {
#pragma unroll
                for (int i = 0; i < 8; ++i) s[f][i] -= u[i];
            }
        }
    };

    int y0 = yc * CHY;
    for (int yy = y0 - 4; yy <= y0 + 4; ++yy)
        if (yy >= 0 && yy < H) tapRow(yy, true);

    double acc = 0.0;
    for (int dy = 0; dy < CHY; ++dy) {
        int y = y0 + dy;
        // stage this y-sum row into LDS (bf16)
#pragma unroll
        for (int f = 0; f < 5; ++f) {
            uint4 o;
            o.x = pack2(s[f][0], s[f][1]);
            o.y = pack2(s[f][2], s[f][3]);
            o.z = pack2(s[f][4], s[f][5]);
            o.w = pack2(s[f][6], s[f][7]);
            *(uint4*)&lds[g][f][8 + x0] = o;
        }
        __syncthreads();

        // x-window sums from LDS: read 24 values covering x in [x0-8, x0+15]
        float wsum[5][8];
#pragma unroll
        for (int f = 0; f < 5; ++f) {
            const uint4* p = (const uint4*)&lds[g][f][x0];
            float v[24];
            unpack8(p[0], v);
            unpack8(p[1], v + 8);
            unpack8(p[2], v + 16);
            float sum = 0.f;
#pragma unroll
            for (int k = 4; k <= 12; ++k) sum += v[k];
            wsum[f][0] = sum;
#pragma unroll
            for (int i = 1; i < 8; ++i) { sum += v[i + 12] - v[i + 3]; wsum[f][i] = sum; }
        }
        __syncthreads();

        // cc + accumulate
#pragma unroll
        for (int i = 0; i < 8; ++i) {
            float Is = wsum[0][i], Js = wsum[1][i];
            float I2s = wsum[2][i], J2s = wsum[3][i], IJs = wsum[4][i];
            float uI = Is * (1.0f / WIN_SIZE);
            float uJ = Js * (1.0f / WIN_SIZE);
            float cross = IJs - uJ * Is - uI * Js + uI * uJ * WIN_SIZE;
            float Ivar  = I2s - 2.0f * uI * Is + uI * uI * WIN_SIZE;
            float Jvar  = J2s - 2.0f * uJ * Js + uJ * uJ * WIN_SIZE;
            acc += (double)(cross * cross / (Ivar * Jvar + 1e-5f));
        }

        // slide y-window
        int ya = y + 5; if (ya < H) tapRow(ya, true);
        int ys = y - 4; if (ys >= 0) tapRow(ys, false);
    }

    // deterministic block reduction (5 waves)
#pragma unroll
    for (int off = 32; off > 0; off >>= 1) acc += __shfl_down(acc, off);
    __shared__ double sm[TPB_YX / 64];
    int lane = tid & 63, wid = tid >> 6;
    if (lane == 0) sm[wid] = acc;
    __syncthreads();
    if (tid == 0) {
        double tt = 0.0;
#pragma unroll
        for (int i = 0; i < TPB_YX / 64; ++i) tt += sm[i];
        partials[blockIdx.x] = tt;
    }
}

// ---- final deterministic reduce ------------------------------------------
__global__ __launch_bounds__(256) void finalize(const double* __restrict__ p,
                                                float* __restrict__ out) {
    double v = 0.0;
    for (int i = threadIdx.x; i < NBLK_YX; i += 256) v += p[i];
#pragma unroll
    for (int off = 32; off > 0; off >>= 1) v += __shfl_down(v, off);
    __shared__ double sm[4];
    int lane = threadIdx.x & 63, wid = threadIdx.x >> 6;
    if (lane == 0) sm[wid] = v;
    __syncthreads();
    if (threadIdx.x == 0) {
        double t = 0.0;
#pragma unroll
        for (int i = 0; i < 4; ++i) t += sm[i];
        out[0] = (float)(1.0 - t / (double)((double)BATCH * (double)NVOX));
    }
}

extern "C" void kernel_launch(void* const* d_in, const int* in_sizes, int n_in,
                              void* d_out, int out_size, void* d_ws, size_t ws_size,
                              hipStream_t stream) {
    const float* I = (const float*)d_in[0];
    const float* J = (const float*)d_in[1];
    float* out = (float*)d_out;

    // ws layout: bufA (2*5*NVOX bf16) | partials (640 f64)
    unsigned short* bufA = (unsigned short*)d_ws;
    double* partials = (double*)(bufA + (size_t)BATCH * 5 * NVOX);

    pass_z<<<NBLK_Z, TPB_Z, 0, stream>>>(I, J, bufA);
    pass_yx<<<NBLK_YX, TPB_YX, 0, stream>>>(bufA, partials);
    finalize<<<1, 256, 0, stream>>>(partials, out);
}

// Round 4
// 95.858 us; speedup vs baseline: 3.3534x; 1.2356x over previous
//
#include <hip/hip_runtime.h>

// NCC loss (B=2, C=1, 160^3 f32, 9^3 box window).
// pass_z : products + sliding z-window sums -> bf16 bufA (5 fields).
// pass_yx: sliding y-window in f32 registers + x-window via wave shuffles
//          (20 lanes = 1 row-tuple, 3 tuples/wave, no LDS, no barriers)
//          + cc expression + deterministic reduction.
// finalize: deterministic reduce of block partials.

constexpr int W = 160, H = 160, D = 160;
constexpr int SLICE = W * H;           // 25600
constexpr int NVOX  = W * H * D;       // 4,096,000
constexpr int BATCH = 2;
constexpr float WIN_SIZE = 729.0f;

// pass_z geometry
constexpr int TPB_Z = 256;
constexpr int XG4   = W / 4;                 // 40 groups of 4 x
constexpr int CHZ   = 5, NCHZ = D / CHZ;     // 32 z-chunks
constexpr int NTH_Z = BATCH * XG4 * H * NCHZ;    // 409,600
constexpr int NBLK_Z = NTH_Z / TPB_Z;            // 1600

// pass_yx geometry
constexpr int TPB_YX = 256;
constexpr int XG  = W / 8;                   // 20 lanes per row-tuple
constexpr int CHY = 5, NCHY = H / CHY;       // 32 y-chunks
constexpr int NTUP = BATCH * D * NCHY;       // 10240 tuples
constexpr int TPW  = 3;                      // tuples per wave (lanes 0..59)
constexpr int TPBLK = 4 * TPW;               // 12 tuples per 256-thread block
constexpr int NBLK_YX = (NTUP + TPBLK - 1) / TPBLK;  // 854

// ---- bf16 helpers --------------------------------------------------------
__device__ inline unsigned short f2bf(float f) {
    unsigned int u = __builtin_bit_cast(unsigned int, f);
    u += 0x7fffu + ((u >> 16) & 1u);
    return (unsigned short)(u >> 16);
}
__device__ inline unsigned int pack2(float lo, float hi) {
    return (unsigned int)f2bf(lo) | ((unsigned int)f2bf(hi) << 16);
}
__device__ inline float bflo(unsigned int u) {
    return __builtin_bit_cast(float, u << 16);
}
__device__ inline float bfhi(unsigned int u) {
    return __builtin_bit_cast(float, u & 0xffff0000u);
}

// ---- pass 1: products + sliding window-sum along z -----------------------
__global__ __launch_bounds__(TPB_Z) void pass_z(const float* __restrict__ I,
                                                const float* __restrict__ J,
                                                unsigned short* __restrict__ outA) {
    int t = blockIdx.x * TPB_Z + threadIdx.x;
    int xg = t % XG4;
    int y  = (t / XG4) % H;
    int c  = (t / (XG4 * H)) % NCHZ;
    int b  = t / (XG4 * H * NCHZ);
    int x0 = xg * 4;
    const float* Ib = I + (size_t)b * NVOX + y * W + x0;
    const float* Jb = J + (size_t)b * NVOX + y * W + x0;
    size_t obase = (size_t)(b * 5) * NVOX + (size_t)y * W + x0;

    float s[5][4];
#pragma unroll
    for (int f = 0; f < 5; ++f)
#pragma unroll
        for (int i = 0; i < 4; ++i) s[f][i] = 0.f;

    auto addS = [&](int zz) {
        float4 a = *(const float4*)(Ib + (size_t)zz * SLICE);
        float4 bb = *(const float4*)(Jb + (size_t)zz * SLICE);
        float av[4] = {a.x, a.y, a.z, a.w};
        float bv[4] = {bb.x, bb.y, bb.z, bb.w};
#pragma unroll
        for (int i = 0; i < 4; ++i) {
            float x = av[i], yv = bv[i];
            s[0][i] += x; s[1][i] += yv;
            s[2][i] += x * x; s[3][i] += yv * yv; s[4][i] += x * yv;
        }
    };
    auto subS = [&](int zz) {
        float4 a = *(const float4*)(Ib + (size_t)zz * SLICE);
        float4 bb = *(const float4*)(Jb + (size_t)zz * SLICE);
        float av[4] = {a.x, a.y, a.z, a.w};
        float bv[4] = {bb.x, bb.y, bb.z, bb.w};
#pragma unroll
        for (int i = 0; i < 4; ++i) {
            float x = av[i], yv = bv[i];
            s[0][i] -= x; s[1][i] -= yv;
            s[2][i] -= x * x; s[3][i] -= yv * yv; s[4][i] -= x * yv;
        }
    };

    int z0 = c * CHZ;
    for (int zz = z0 - 4 < 0 ? 0 : z0 - 4; zz <= z0 + 4; ++zz) addS(zz);

    for (int dz = 0; dz < CHZ; ++dz) {
        int z = z0 + dz;
#pragma unroll
        for (int f = 0; f < 5; ++f) {
            uint2 o;
            o.x = pack2(s[f][0], s[f][1]);
            o.y = pack2(s[f][2], s[f][3]);
            *(uint2*)(outA + obase + (size_t)f * NVOX + (size_t)z * SLICE) = o;
        }
        int za = z + 5; if (za < D) addS(za);
        int zs = z - 4; if (zs >= 0) subS(zs);
    }
}

// ---- pass 2: y-window (regs) + x-window (shuffles) + cc + reduce ---------
__global__ __launch_bounds__(TPB_YX) void pass_yx(const unsigned short* __restrict__ A,
                                                  double* __restrict__ partials) {
    int tid = threadIdx.x;
    int lane = tid & 63, wv = tid >> 6;
    int g = lane / XG, xg = lane % XG;          // g==3 -> idle lanes 60..63
    int tuple = blockIdx.x * TPBLK + wv * TPW + g;
    bool valid = (g < TPW) && (tuple < NTUP);
    int t = valid ? tuple : 0;
    int yc = t % NCHY;
    int z  = (t / NCHY) % D;
    int b  = t / (NCHY * D);
    int x0 = xg * 8;
    const unsigned short* __restrict__ base =
        A + (size_t)(b * 5) * NVOX + (size_t)z * SLICE + x0;
    int y0 = yc * CHY;

    float s[5][8];
#pragma unroll
    for (int f = 0; f < 5; ++f)
#pragma unroll
        for (int i = 0; i < 8; ++i) s[f][i] = 0.f;

    // initial y-window: rows y0-4 .. y0+4 (upper bound always < H)
    for (int yy = (y0 - 4 < 0 ? 0 : y0 - 4); yy <= y0 + 4; ++yy) {
#pragma unroll
        for (int f = 0; f < 5; ++f) {
            uint4 v = *(const uint4*)(base + (size_t)f * NVOX + (size_t)yy * W);
            s[f][0] += bflo(v.x); s[f][1] += bfhi(v.x);
            s[f][2] += bflo(v.y); s[f][3] += bfhi(v.y);
            s[f][4] += bflo(v.z); s[f][5] += bfhi(v.z);
            s[f][6] += bflo(v.w); s[f][7] += bfhi(v.w);
        }
    }

    double acc = 0.0;
    for (int dy = 0; dy < CHY; ++dy) {
        int ye = y0 + dy + 5, yl = y0 + dy - 4;
        bool he = ye < H, hl = yl >= 0;
        uint4 pe[5], pl[5];
#pragma unroll
        for (int f = 0; f < 5; ++f) {
            pe[f] = he ? *(const uint4*)(base + (size_t)f * NVOX + (size_t)ye * W)
                       : make_uint4(0u, 0u, 0u, 0u);
            pl[f] = hl ? *(const uint4*)(base + (size_t)f * NVOX + (size_t)yl * W)
                       : make_uint4(0u, 0u, 0u, 0u);
        }

        // x-window sums from current s via prefix + neighbor-lane shuffles
        float wv5[5][8];
#pragma unroll
        for (int f = 0; f < 5; ++f) {
            float p0 = s[f][0];
            float p1 = p0 + s[f][1];
            float p2 = p1 + s[f][2];
            float p3 = p2 + s[f][3];
            float p4 = p3 + s[f][4];
            float p5 = p4 + s[f][5];
            float p6 = p5 + s[f][6];
            float tot = p6 + s[f][7];
            float a0 = tot - p3, a1 = tot - p4, a2 = tot - p5, a3 = tot - p6;
            float L0 = __shfl_up(a0, 1), L1 = __shfl_up(a1, 1);
            float L2 = __shfl_up(a2, 1), L3 = __shfl_up(a3, 1);
            float R0 = __shfl_down(p0, 1), R1 = __shfl_down(p1, 1);
            float R2 = __shfl_down(p2, 1), R3 = __shfl_down(p3, 1);
            if (xg == 0)      { L0 = 0.f; L1 = 0.f; L2 = 0.f; L3 = 0.f; }
            if (xg == XG - 1) { R0 = 0.f; R1 = 0.f; R2 = 0.f; R3 = 0.f; }
            wv5[f][0] = L0 + p4;
            wv5[f][1] = L1 + p5;
            wv5[f][2] = L2 + p6;
            wv5[f][3] = L3 + tot;
            wv5[f][4] = tot + R0;
            wv5[f][5] = (tot - p0) + R1;
            wv5[f][6] = (tot - p1) + R2;
            wv5[f][7] = (tot - p2) + R3;
        }

        float rowcc = 0.f;
#pragma unroll
        for (int i = 0; i < 8; ++i) {
            float Is = wv5[0][i], Js = wv5[1][i];
            float I2s = wv5[2][i], J2s = wv5[3][i], IJs = wv5[4][i];
            float uI = Is * (1.0f / WIN_SIZE);
            float uJ = Js * (1.0f / WIN_SIZE);
            float cross = IJs - uJ * Is - uI * Js + uI * uJ * WIN_SIZE;
            float Iv = I2s - 2.0f * uI * Is + uI * uI * WIN_SIZE;
            float Jv = J2s - 2.0f * uJ * Js + uJ * uJ * WIN_SIZE;
            rowcc += cross * cross / (Iv * Jv + 1e-5f);
        }
        acc += (double)rowcc;

        // slide the y-window
#pragma unroll
        for (int f = 0; f < 5; ++f) {
            s[f][0] += bflo(pe[f].x) - bflo(pl[f].x);
            s[f][1] += bfhi(pe[f].x) - bfhi(pl[f].x);
            s[f][2] += bflo(pe[f].y) - bflo(pl[f].y);
            s[f][3] += bfhi(pe[f].y) - bfhi(pl[f].y);
            s[f][4] += bflo(pe[f].z) - bflo(pl[f].z);
            s[f][5] += bfhi(pe[f].z) - bfhi(pl[f].z);
            s[f][6] += bflo(pe[f].w) - bflo(pl[f].w);
            s[f][7] += bfhi(pe[f].w) - bfhi(pl[f].w);
        }
    }

    if (!valid) acc = 0.0;

    // deterministic block reduction
#pragma unroll
    for (int off = 32; off > 0; off >>= 1) acc += __shfl_down(acc, off);
    __shared__ double sm[TPB_YX / 64];
    if ((tid & 63) == 0) sm[tid >> 6] = acc;
    __syncthreads();
    if (tid == 0) {
        double tt = 0.0;
#pragma unroll
        for (int i = 0; i < TPB_YX / 64; ++i) tt += sm[i];
        partials[blockIdx.x] = tt;
    }
}

// ---- final deterministic reduce ------------------------------------------
__global__ __launch_bounds__(256) void finalize(const double* __restrict__ p,
                                                float* __restrict__ out) {
    double v = 0.0;
    for (int i = threadIdx.x; i < NBLK_YX; i += 256) v += p[i];
#pragma unroll
    for (int off = 32; off > 0; off >>= 1) v += __shfl_down(v, off);
    __shared__ double sm[4];
    int lane = threadIdx.x & 63, wid = threadIdx.x >> 6;
    if (lane == 0) sm[wid] = v;
    __syncthreads();
    if (threadIdx.x == 0) {
        double t = 0.0;
#pragma unroll
        for (int i = 0; i < 4; ++i) t += sm[i];
        out[0] = (float)(1.0 - t / (double)((double)BATCH * (double)NVOX));
    }
}

extern "C" void kernel_launch(void* const* d_in, const int* in_sizes, int n_in,
                              void* d_out, int out_size, void* d_ws, size_t ws_size,
                              hipStream_t stream) {
    const float* I = (const float*)d_in[0];
    const float* J = (const float*)d_in[1];
    float* out = (float*)d_out;

    // ws layout: bufA (2*5*NVOX bf16) | partials (NBLK_YX f64)
    unsigned short* bufA = (unsigned short*)d_ws;
    double* partials = (double*)(bufA + (size_t)BATCH * 5 * NVOX);

    pass_z<<<NBLK_Z, TPB_Z, 0, stream>>>(I, J, bufA);
    pass_yx<<<NBLK_YX, TPB_YX, 0, stream>>>(bufA, partials);
    finalize<<<1, 256, 0, stream>>>(partials, out);
}

// Round 5
// 68.343 us; speedup vs baseline: 4.7035x; 1.4026x over previous
//
#include <hip/hip_runtime.h>

// NCC loss (B=2, C=1, 160^3 f32, 9^3 box window).
// pass_z : products + sliding z-window sums -> fp8(e4m3) bufA, layout
//          [b][z][y][field][x] (800 B per (z,y) row-group).
// pass_yx: sliding y-window in f32 registers + x-window via wave shuffles
//          (20 lanes = 1 row-tuple, 3 tuples/wave) + cc + reduction.
// finalize: deterministic reduce of block partials.

typedef float floatx2 __attribute__((ext_vector_type(2)));

constexpr int W = 160, H = 160, D = 160;
constexpr int SLICE = W * H;           // 25600
constexpr int NVOX  = W * H * D;       // 4,096,000
constexpr int BATCH = 2;
constexpr int FROW  = 5 * W;           // 800 fp8 bytes per (z,y) row-group
constexpr float RW  = 1.0f / 729.0f;

// pass_z geometry
constexpr int TPB_Z = 256;
constexpr int XG4   = W / 4;                     // 40 groups of 4 x
constexpr int CHZ   = 8, NCHZ = D / CHZ;         // 20 z-chunks
constexpr int NTH_Z = BATCH * XG4 * H * NCHZ;    // 256,000
constexpr int NBLK_Z = NTH_Z / TPB_Z;            // 1000

// pass_yx geometry
constexpr int TPB_YX = 256;
constexpr int XG  = W / 8;                       // 20 lanes per row-tuple
constexpr int CHY = 4, NCHY = H / CHY;           // 40 y-chunks
constexpr int NTUP = BATCH * D * NCHY;           // 12,800 tuples
constexpr int TPW  = 3;                          // tuples per wave
constexpr int TPBLK = 4 * TPW;                   // 12 tuples per block
constexpr int NBLK_YX = (NTUP + TPBLK - 1) / TPBLK;  // 1067

// ---- fp8 helpers (HW cvt, OCP e4m3 on gfx950) ----------------------------
__device__ inline unsigned int pk4(float a, float b, float c, float d) {
    unsigned int u = 0;
    u = __builtin_amdgcn_cvt_pk_fp8_f32(a, b, u, false);  // bytes 0,1
    u = __builtin_amdgcn_cvt_pk_fp8_f32(c, d, u, true);   // bytes 2,3
    return u;
}
__device__ inline void up8(uint2 v, float* o) {
    floatx2 t;
    t = __builtin_amdgcn_cvt_pk_f32_fp8(v.x, false); o[0] = t[0]; o[1] = t[1];
    t = __builtin_amdgcn_cvt_pk_f32_fp8(v.x, true);  o[2] = t[0]; o[3] = t[1];
    t = __builtin_amdgcn_cvt_pk_f32_fp8(v.y, false); o[4] = t[0]; o[5] = t[1];
    t = __builtin_amdgcn_cvt_pk_f32_fp8(v.y, true);  o[6] = t[0]; o[7] = t[1];
}

// ---- pass 1: products + sliding window-sum along z -----------------------
__global__ __launch_bounds__(TPB_Z) void pass_z(const float* __restrict__ I,
                                                const float* __restrict__ J,
                                                unsigned char* __restrict__ outA) {
    int t = blockIdx.x * TPB_Z + threadIdx.x;
    int xg = t % XG4;
    int y  = (t / XG4) % H;
    int c  = (t / (XG4 * H)) % NCHZ;
    int b  = t / (XG4 * H * NCHZ);
    int x0 = xg * 4;
    const float* Ib = I + (size_t)b * NVOX + y * W + x0;
    const float* Jb = J + (size_t)b * NVOX + y * W + x0;
    unsigned char* ob = outA + ((size_t)b * D * H + y) * FROW + x0;

    float s[5][4];
#pragma unroll
    for (int f = 0; f < 5; ++f)
#pragma unroll
        for (int i = 0; i < 4; ++i) s[f][i] = 0.f;

    auto addS = [&](int zz) {
        float4 a = *(const float4*)(Ib + (size_t)zz * SLICE);
        float4 bb = *(const float4*)(Jb + (size_t)zz * SLICE);
        float av[4] = {a.x, a.y, a.z, a.w};
        float bv[4] = {bb.x, bb.y, bb.z, bb.w};
#pragma unroll
        for (int i = 0; i < 4; ++i) {
            float x = av[i], yv = bv[i];
            s[0][i] += x; s[1][i] += yv;
            s[2][i] += x * x; s[3][i] += yv * yv; s[4][i] += x * yv;
        }
    };

    int z0 = c * CHZ;
    for (int zz = (z0 - 4 < 0 ? 0 : z0 - 4); zz <= z0 + 4; ++zz) addS(zz);

#pragma unroll
    for (int dz = 0; dz < CHZ; ++dz) {
        int z = z0 + dz;
        int za = z + 5, zs = z - 4;
        bool ha = za < D, hs = zs >= 0;
        // issue next-tap loads first (branchless, zero-guarded)
        float4 Az = ha ? *(const float4*)(Ib + (size_t)za * SLICE) : make_float4(0.f, 0.f, 0.f, 0.f);
        float4 Bz = ha ? *(const float4*)(Jb + (size_t)za * SLICE) : make_float4(0.f, 0.f, 0.f, 0.f);
        float4 As = hs ? *(const float4*)(Ib + (size_t)zs * SLICE) : make_float4(0.f, 0.f, 0.f, 0.f);
        float4 Bs = hs ? *(const float4*)(Jb + (size_t)zs * SLICE) : make_float4(0.f, 0.f, 0.f, 0.f);

        // store current sums (fp8, interleaved layout)
        unsigned char* op = ob + (size_t)z * (H * FROW);
#pragma unroll
        for (int f = 0; f < 5; ++f)
            *(unsigned int*)(op + f * W) = pk4(s[f][0], s[f][1], s[f][2], s[f][3]);

        // slide the z-window
        float ae[4] = {Az.x, Az.y, Az.z, Az.w};
        float be[4] = {Bz.x, Bz.y, Bz.z, Bz.w};
        float al[4] = {As.x, As.y, As.z, As.w};
        float bl[4] = {Bs.x, Bs.y, Bs.z, Bs.w};
#pragma unroll
        for (int i = 0; i < 4; ++i) {
            s[0][i] += ae[i] - al[i];
            s[1][i] += be[i] - bl[i];
            s[2][i] += ae[i] * ae[i] - al[i] * al[i];
            s[3][i] += be[i] * be[i] - bl[i] * bl[i];
            s[4][i] += ae[i] * be[i] - al[i] * bl[i];
        }
    }
}

// ---- pass 2: y-window (regs) + x-window (shuffles) + cc + reduce ---------
__global__ __launch_bounds__(TPB_YX) void pass_yx(const unsigned char* __restrict__ A,
                                                  double* __restrict__ partials) {
    int tid = threadIdx.x;
    int lane = tid & 63, wvi = tid >> 6;
    int g = lane / XG, xg = lane % XG;          // g==3 -> idle lanes 60..63
    int tuple = blockIdx.x * TPBLK + wvi * TPW + g;
    bool valid = (g < TPW) && (tuple < NTUP);
    int t = valid ? tuple : 0;
    int yc = t % NCHY;
    int z  = (t / NCHY) % D;
    int b  = t / (NCHY * D);
    int x0 = xg * 8;
    const unsigned char* __restrict__ base =
        A + (size_t)(b * D + z) * H * FROW + x0;
    int y0 = yc * CHY;

    float s[5][8];
#pragma unroll
    for (int f = 0; f < 5; ++f)
#pragma unroll
        for (int i = 0; i < 8; ++i) s[f][i] = 0.f;

    // initial y-window: rows y0-4 .. y0+4 (clamped)
    int ylo = y0 - 4 < 0 ? 0 : y0 - 4;
    int yhi = y0 + 4 > H - 1 ? H - 1 : y0 + 4;
    for (int yy = ylo; yy <= yhi; ++yy) {
        const unsigned char* rp = base + (size_t)yy * FROW;
#pragma unroll
        for (int f = 0; f < 5; ++f) {
            uint2 v = *(const uint2*)(rp + f * W);
            float u[8]; up8(v, u);
#pragma unroll
            for (int i = 0; i < 8; ++i) s[f][i] += u[i];
        }
    }

    double acc = 0.0;
#pragma unroll
    for (int dy = 0; dy < CHY; ++dy) {
        int ye = y0 + dy + 5, yl = y0 + dy - 4;
        bool he = ye < H, hl = yl >= 0;
        uint2 pe[5], pl[5];
        const unsigned char* pre = base + (size_t)(he ? ye : 0) * FROW;
        const unsigned char* prl = base + (size_t)(hl ? yl : 0) * FROW;
#pragma unroll
        for (int f = 0; f < 5; ++f) {
            pe[f] = he ? *(const uint2*)(pre + f * W) : make_uint2(0u, 0u);
            pl[f] = hl ? *(const uint2*)(prl + f * W) : make_uint2(0u, 0u);
        }

        // x-window sums from current s via prefix + neighbor-lane shuffles
        float wv5[5][8];
#pragma unroll
        for (int f = 0; f < 5; ++f) {
            float p0 = s[f][0];
            float p1 = p0 + s[f][1];
            float p2 = p1 + s[f][2];
            float p3 = p2 + s[f][3];
            float p4 = p3 + s[f][4];
            float p5 = p4 + s[f][5];
            float p6 = p5 + s[f][6];
            float tot = p6 + s[f][7];
            float a0 = tot - p3, a1 = tot - p4, a2 = tot - p5, a3 = tot - p6;
            float L0 = __shfl_up(a0, 1), L1 = __shfl_up(a1, 1);
            float L2 = __shfl_up(a2, 1), L3 = __shfl_up(a3, 1);
            float R0 = __shfl_down(p0, 1), R1 = __shfl_down(p1, 1);
            float R2 = __shfl_down(p2, 1), R3 = __shfl_down(p3, 1);
            if (xg == 0)      { L0 = 0.f; L1 = 0.f; L2 = 0.f; L3 = 0.f; }
            if (xg == XG - 1) { R0 = 0.f; R1 = 0.f; R2 = 0.f; R3 = 0.f; }
            wv5[f][0] = L0 + p4;
            wv5[f][1] = L1 + p5;
            wv5[f][2] = L2 + p6;
            wv5[f][3] = L3 + tot;
            wv5[f][4] = tot + R0;
            wv5[f][5] = (tot - p0) + R1;
            wv5[f][6] = (tot - p1) + R2;
            wv5[f][7] = (tot - p2) + R3;
        }

        float rowcc = 0.f;
#pragma unroll
        for (int i = 0; i < 8; ++i) {
            float Is = wv5[0][i], Js = wv5[1][i];
            float I2s = wv5[2][i], J2s = wv5[3][i], IJs = wv5[4][i];
            float tI = RW * Is;
            float cross = __builtin_fmaf(-tI, Js, IJs);       // IJs - Is*Js/729
            float Iv    = __builtin_fmaf(-tI, Is, I2s);       // I2s - Is^2/729
            float Jv    = __builtin_fmaf(-(RW * Js), Js, J2s);
            float den   = __builtin_fmaf(Iv, Jv, 1e-5f);
            rowcc = __builtin_fmaf(cross * cross, __builtin_amdgcn_rcpf(den), rowcc);
        }
        acc += (double)rowcc;

        // slide the y-window
#pragma unroll
        for (int f = 0; f < 5; ++f) {
            float ue[8], ul[8];
            up8(pe[f], ue); up8(pl[f], ul);
#pragma unroll
            for (int i = 0; i < 8; ++i) s[f][i] += ue[i] - ul[i];
        }
    }

    if (!valid) acc = 0.0;

    // deterministic block reduction
#pragma unroll
    for (int off = 32; off > 0; off >>= 1) acc += __shfl_down(acc, off);
    __shared__ double sm[TPB_YX / 64];
    if ((tid & 63) == 0) sm[tid >> 6] = acc;
    __syncthreads();
    if (tid == 0) {
        double tt = 0.0;
#pragma unroll
        for (int i = 0; i < TPB_YX / 64; ++i) tt += sm[i];
        partials[blockIdx.x] = tt;
    }
}

// ---- final deterministic reduce ------------------------------------------
__global__ __launch_bounds__(256) void finalize(const double* __restrict__ p,
                                                float* __restrict__ out) {
    double v = 0.0;
    for (int i = threadIdx.x; i < NBLK_YX; i += 256) v += p[i];
#pragma unroll
    for (int off = 32; off > 0; off >>= 1) v += __shfl_down(v, off);
    __shared__ double sm[4];
    int lane = threadIdx.x & 63, wid = threadIdx.x >> 6;
    if (lane == 0) sm[wid] = v;
    __syncthreads();
    if (threadIdx.x == 0) {
        double tt = 0.0;
#pragma unroll
        for (int i = 0; i < 4; ++i) tt += sm[i];
        out[0] = (float)(1.0 - tt / (double)((double)BATCH * (double)NVOX));
    }
}

extern "C" void kernel_launch(void* const* d_in, const int* in_sizes, int n_in,
                              void* d_out, int out_size, void* d_ws, size_t ws_size,
                              hipStream_t stream) {
    const float* I = (const float*)d_in[0];
    const float* J = (const float*)d_in[1];
    float* out = (float*)d_out;

    // ws layout: bufA (BATCH*5*NVOX fp8 bytes = 41 MB) | partials (NBLK_YX f64)
    unsigned char* bufA = (unsigned char*)d_ws;
    double* partials = (double*)(bufA + ((size_t)BATCH * 5 * NVOX + 255) / 256 * 256);

    pass_z<<<NBLK_Z, TPB_Z, 0, stream>>>(I, J, bufA);
    pass_yx<<<NBLK_YX, TPB_YX, 0, stream>>>(bufA, partials);
    finalize<<<1, 256, 0, stream>>>(partials, out);
}